// Round 5
// baseline (1388.383 us; speedup 1.0000x reference)
//
#include <hip/hip_runtime.h>

typedef __bf16 bf16x8 __attribute__((ext_vector_type(8)));
typedef float f32x4 __attribute__((ext_vector_type(4)));

typedef const unsigned int __attribute__((address_space(1)))* gas_p;
typedef unsigned int __attribute__((address_space(3)))* las_p;

__device__ __forceinline__ void gload_lds16(const void* g, void* l) {
  __builtin_amdgcn_global_load_lds((gas_p)g, (las_p)l, 16, 0, 0);
}

__device__ __forceinline__ unsigned short f2bf(float f) {
  union { float f; unsigned int u; } x; x.f = f;
  unsigned int r = x.u + 0x7fffu + ((x.u >> 16) & 1u);
  return (unsigned short)(r >> 16);
}
__device__ __forceinline__ float elu1(float x) {
  return x > 0.f ? x + 1.f : __expf(x);
}
__device__ __forceinline__ f32x4 mfma16(bf16x8 a, bf16x8 b, f32x4 c) {
  return __builtin_amdgcn_mfma_f32_16x16x32_bf16(a, b, c, 0, 0, 0);
}

#define BAR() __builtin_amdgcn_s_barrier()
#define VMW8() asm volatile("s_waitcnt vmcnt(8)" ::: "memory")
#define VMW4() asm volatile("s_waitcnt vmcnt(4)" ::: "memory")
#define VMW2() asm volatile("s_waitcnt vmcnt(2)" ::: "memory")
#define VMW0() asm volatile("s_waitcnt vmcnt(0)" ::: "memory")
#define LGKM0() do { asm volatile("s_waitcnt lgkmcnt(0)" ::: "memory"); \
                     __builtin_amdgcn_sched_barrier(0); } while (0)

// ---------------- weight transpose/convert ----------------

__global__ __launch_bounds__(256) void k_cvt_t(const float* __restrict__ w,
                                               unsigned short* __restrict__ wT,
                                               int R, int Cc) {
  __shared__ float t[32][33];
  const int j0 = blockIdx.x * 32, i0 = blockIdx.y * 32;
  const int tx = threadIdx.x & 31, ty = threadIdx.x >> 5;
#pragma unroll
  for (int k = 0; k < 4; ++k)
    t[ty + 8 * k][tx] = w[(size_t)(i0 + ty + 8 * k) * Cc + j0 + tx];
  __syncthreads();
#pragma unroll
  for (int k = 0; k < 4; ++k)
    wT[(size_t)(j0 + ty + 8 * k) * R + i0 + tx] = f2bf(t[tx][ty + 8 * k]);
}

// ---------------- qkv GEMM: A = x (f32, converted in-kernel), 64 KiB LDS, 2 blk/CU ----
// LDS: per operand 2 slots of [256 rows][32 K] bf16 (16 KiB). slot = pair parity (h).
// A staged via regs (f32 load -> f2bf -> swizzled ds_write); B via global_load_lds with
// inverse-swizzled source (rule 21). Read swizzle: col ^= ((row>>1)&3)<<3 elems.

__global__ __launch_bounds__(512, 4) void k_gemmq(
    const float* __restrict__ X, const unsigned short* __restrict__ BT,
    unsigned short* __restrict__ qb, unsigned short* __restrict__ kT,
    unsigned short* __restrict__ vT) {
  extern __shared__ unsigned short lds[];
  unsigned short* Asb = lds;            // slots at 0, 8192 elems
  unsigned short* Bsb = lds + 16384;    // slots at 0, 8192 elems

  const int tid = threadIdx.x, lane = tid & 63, wave = tid >> 6;
  const int wm = wave >> 2, wn = wave & 3;
  int bid = blockIdx.x;
  { const int cpx = (int)gridDim.x >> 3; bid = (bid & 7) * cpx + (bid >> 3); }
  const int bx = bid % 12, by = bid / 12;
  const size_t bm0 = (size_t)by << 8, bn0 = (size_t)bx << 8;

  // staging geometry: thread covers rows {srow, srow+128}, 8 elems at col8 within [256][32]
  const int srow = (wave << 4) + (lane >> 2);
  const int col8 = (lane & 3) << 3;
  const int swkey = ((srow >> 1) & 3) << 3;  // same for srow and srow+128
  // B source (inverse-swizzled global col), DMA to linear LDS:
  const unsigned short* Bg0 = BT + (bn0 + srow) * 1024 + (col8 ^ swkey);
  unsigned short* Bl0 = Bsb + (wave << 9);
  // A source natural col; A LDS dest swizzled:
  const float* Xg0 = X + (bm0 + srow) * 1024 + col8;
  unsigned short* Al0 = Asb + srow * 32 + (col8 ^ swkey);

  auto issueB = [&](int slot, int kcol) {
    const unsigned short* g_ = Bg0 + kcol;
    unsigned short* l_ = Bl0 + (slot << 13);
    gload_lds16(g_, l_);
    gload_lds16(g_ + 128 * 1024, l_ + 4096);
  };

  float4 fa0, fa1, fa2, fa3;
  auto issueA = [&](int kcol) {
    const float* g_ = Xg0 + kcol;
    fa0 = *(const float4*)(g_);
    fa1 = *(const float4*)(g_ + 4);
    fa2 = *(const float4*)(g_ + 128 * 1024);
    fa3 = *(const float4*)(g_ + 128 * 1024 + 4);
  };
  auto cvtWrite = [&](int slot) {
    union { unsigned short u[8]; uint4 q; } p0, p1;
    p0.u[0] = f2bf(fa0.x); p0.u[1] = f2bf(fa0.y); p0.u[2] = f2bf(fa0.z); p0.u[3] = f2bf(fa0.w);
    p0.u[4] = f2bf(fa1.x); p0.u[5] = f2bf(fa1.y); p0.u[6] = f2bf(fa1.z); p0.u[7] = f2bf(fa1.w);
    p1.u[0] = f2bf(fa2.x); p1.u[1] = f2bf(fa2.y); p1.u[2] = f2bf(fa2.z); p1.u[3] = f2bf(fa2.w);
    p1.u[4] = f2bf(fa3.x); p1.u[5] = f2bf(fa3.y); p1.u[6] = f2bf(fa3.z); p1.u[7] = f2bf(fa3.w);
    unsigned short* l_ = Al0 + (slot << 13);
    *(uint4*)l_ = p0.q;
    *(uint4*)(l_ + 128 * 32) = p1.q;
  };

  // fragment read addressing
  const int q8 = ((lane >> 4) << 3) ^ (((lane >> 1) & 3) << 3);
  const int ar_base = (wm << 7) + (lane & 15);
  const int br_base = (wn << 6) + (lane & 15);

  f32x4 acc[8][4] = {};  // [rh*4+mi][n]

  // prologue: pair 0 (tile0, h0) into slot 0
  issueA(0);
  issueB(0, 0);
  VMW2();           // A f32 landed (4 loads), B's 2 still in flight
  cvtWrite(0);
  VMW0();           // B(0) landed
  LGKM0();          // ds_writes drained
  BAR();

  for (int t = 0; t < 16; ++t) {
    const int kc0 = t << 6;
    bf16x8 af[4], bfr[4];

    // ---- P0: slot0 rh0; issue pair 2t+1 (h1) -> slot1 ----
#pragma unroll
    for (int mi = 0; mi < 4; ++mi)
      af[mi] = *(const bf16x8*)&Asb[((ar_base + mi * 16) << 5) + q8];
#pragma unroll
    for (int n = 0; n < 4; ++n)
      bfr[n] = *(const bf16x8*)&Bsb[((br_base + n * 16) << 5) + q8];
    issueA(kc0 + 32);
    issueB(1, kc0 + 32);
    BAR();
    __builtin_amdgcn_s_setprio(1);
#pragma unroll
    for (int mi = 0; mi < 4; ++mi)
#pragma unroll
      for (int n = 0; n < 4; ++n) acc[mi][n] = mfma16(af[mi], bfr[n], acc[mi][n]);
    __builtin_amdgcn_s_setprio(0);
    BAR();

    // ---- P1: slot0 rh1; cvt-write A -> slot1 ----
#pragma unroll
    for (int mi = 0; mi < 4; ++mi)
      af[mi] = *(const bf16x8*)&Asb[((ar_base + 64 + mi * 16) << 5) + q8];
    VMW2();          // A f32 (pair 2t+1) landed
    cvtWrite(1);
    LGKM0();
    BAR();
    __builtin_amdgcn_s_setprio(1);
#pragma unroll
    for (int mi = 0; mi < 4; ++mi)
#pragma unroll
      for (int n = 0; n < 4; ++n) acc[4 + mi][n] = mfma16(af[mi], bfr[n], acc[4 + mi][n]);
    __builtin_amdgcn_s_setprio(0);
    VMW0();          // B (pair 2t+1) landed
    BAR();

    // ---- P2: slot1 rh0; issue pair 2t+2 (tile t+1, h0) -> slot0 ----
#pragma unroll
    for (int mi = 0; mi < 4; ++mi)
      af[mi] = *(const bf16x8*)&Asb[8192 + ((ar_base + mi * 16) << 5) + q8];
#pragma unroll
    for (int n = 0; n < 4; ++n)
      bfr[n] = *(const bf16x8*)&Bsb[8192 + ((br_base + n * 16) << 5) + q8];
    if (t < 15) {
      issueA(kc0 + 64);
      issueB(0, kc0 + 64);
    }
    BAR();
    __builtin_amdgcn_s_setprio(1);
#pragma unroll
    for (int mi = 0; mi < 4; ++mi)
#pragma unroll
      for (int n = 0; n < 4; ++n) acc[mi][n] = mfma16(af[mi], bfr[n], acc[mi][n]);
    __builtin_amdgcn_s_setprio(0);
    BAR();

    // ---- P3: slot1 rh1; cvt-write A -> slot0 ----
#pragma unroll
    for (int mi = 0; mi < 4; ++mi)
      af[mi] = *(const bf16x8*)&Asb[8192 + ((ar_base + 64 + mi * 16) << 5) + q8];
    if (t < 15) {
      VMW2();        // A f32 (pair 2t+2) landed
      cvtWrite(0);
    }
    LGKM0();
    BAR();
    __builtin_amdgcn_s_setprio(1);
#pragma unroll
    for (int mi = 0; mi < 4; ++mi)
#pragma unroll
      for (int n = 0; n < 4; ++n) acc[4 + mi][n] = mfma16(af[mi], bfr[n], acc[4 + mi][n]);
    __builtin_amdgcn_s_setprio(0);
    if (t < 15) VMW0();  // B (pair 2t+2) landed
    BAR();
  }

  // ---- epilogue: elu+1 on q,k; scatter k,v to [bh][d][n] ----
  const int rbase = (int)bm0 + (wm << 7) + ((lane >> 4) << 2);
  const int cbase = (int)bn0 + (wn << 6) + (lane & 15);
  const int reg3 = (int)(bn0 >> 10);  // 0=q 1=k 2=v, uniform per block
#pragma unroll
  for (int m = 0; m < 8; ++m) {
    const int rb = rbase + m * 16;
#pragma unroll
    for (int n = 0; n < 4; ++n) {
      const int col = cbase + n * 16;
      if (reg3 == 0) {
#pragma unroll
        for (int i = 0; i < 4; ++i)
          qb[(size_t)(rb + i) * 1024 + col] = f2bf(elu1(acc[m][n][i]));
      } else {
        const int jc = col & 1023, h = jc >> 6, d = jc & 63;
        const int b_ = rb >> 12, n_ = rb & 4095;
        union { unsigned short u[4]; uint2 q; } pk;
        if (reg3 == 1) {
#pragma unroll
          for (int i = 0; i < 4; ++i) pk.u[i] = f2bf(elu1(acc[m][n][i]));
        } else {
#pragma unroll
          for (int i = 0; i < 4; ++i) pk.u[i] = f2bf(acc[m][n][i]);
        }
        unsigned short* dst = (reg3 == 1) ? kT : vT;
        *(uint2*)(dst + ((size_t)((b_ * 16 + h) * 64 + d) * 4096 + n_)) = pk.q;
      }
    }
  }
}

// ---------------- proj GEMM: ring-4 half-pair deep pipeline (unchanged, EPI=1) --------

__global__ __launch_bounds__(512, 2) void k_gemmp(
    const unsigned short* __restrict__ A, const unsigned short* __restrict__ BT,
    const float* __restrict__ bias, float* __restrict__ out) {
  extern __shared__ unsigned short lds[];
  unsigned short* Asb = lds;
  unsigned short* Bsb = lds + 32768;

  const int tid = threadIdx.x, lane = tid & 63, wave = tid >> 6;
  const int wm = wave >> 2, wn = wave & 3;
  int bid = blockIdx.x;
  { const int cpx = (int)gridDim.x >> 3; bid = (bid & 7) * cpx + (bid >> 3); }
  const int bx = bid % 4, by = bid / 4;
  const size_t bm0 = (size_t)by << 8, bn0 = (size_t)bx << 8;

  const int srow = (wave << 4) + (lane >> 2);
  const int gscol = ((lane & 3) << 3) ^ (((srow >> 1) & 3) << 3);
  const unsigned short* Ag0 = A + (bm0 + srow) * 1024 + gscol;
  const unsigned short* Bg0 = BT + (bn0 + srow) * 1024 + gscol;
  const int lws = wave << 9;

  auto stageA = [&](int slot, int kt, int kh) {
    const unsigned short* g_ = Ag0 + (kt << 6) + (kh << 5);
    unsigned short* l_ = Asb + (slot << 13) + lws;
    gload_lds16(g_, l_);
    gload_lds16(g_ + 128 * 1024, l_ + 4096);
  };
  auto stageB = [&](int slot, int kt, int kh) {
    const unsigned short* g_ = Bg0 + (kt << 6) + (kh << 5);
    unsigned short* l_ = Bsb + (slot << 13) + lws;
    gload_lds16(g_, l_);
    gload_lds16(g_ + 128 * 1024, l_ + 4096);
  };

  const int q8 = ((lane >> 4) << 3) ^ (((lane >> 1) & 3) << 3);
  const int ar_base = (wm << 7) + (lane & 15);
  const int br_base = (wn << 6) + (lane & 15);

  f32x4 acc[8][4] = {};

  stageA(0, 0, 0); stageB(0, 0, 0);
  stageA(1, 0, 1); stageB(1, 0, 1);
  stageA(2, 1, 0); stageB(2, 1, 0);
  VMW8();
  BAR();

#pragma unroll
  for (int t = 0; t < 16; ++t) {
    const int s0 = (2 * t) & 3, s1 = (2 * t + 1) & 3;
    const int sA = (2 * t + 3) & 3, sB = (2 * t + 4) & 3;
    const int t1 = t + 1, t2 = (t + 2 > 15) ? 15 : t + 2;
    bf16x8 af[4], bfr[4];

#pragma unroll
    for (int mi = 0; mi < 4; ++mi)
      af[mi] = *(const bf16x8*)&Asb[(s0 << 13) + ((ar_base + mi * 16) << 5) + q8];
#pragma unroll
    for (int n = 0; n < 4; ++n)
      bfr[n] = *(const bf16x8*)&Bsb[(s0 << 13) + ((br_base + n * 16) << 5) + q8];
    if (t < 15) stageA(sA, t1, 1);
    BAR();
    __builtin_amdgcn_s_setprio(1);
#pragma unroll
    for (int mi = 0; mi < 4; ++mi)
#pragma unroll
      for (int n = 0; n < 4; ++n) acc[mi][n] = mfma16(af[mi], bfr[n], acc[mi][n]);
    __builtin_amdgcn_s_setprio(0);
    BAR();

#pragma unroll
    for (int mi = 0; mi < 4; ++mi)
      af[mi] = *(const bf16x8*)&Asb[(s0 << 13) + ((ar_base + 64 + mi * 16) << 5) + q8];
    if (t < 15) stageB(sA, t1, 1);
    BAR();
    __builtin_amdgcn_s_setprio(1);
#pragma unroll
    for (int mi = 0; mi < 4; ++mi)
#pragma unroll
      for (int n = 0; n < 4; ++n) acc[4 + mi][n] = mfma16(af[mi], bfr[n], acc[4 + mi][n]);
    __builtin_amdgcn_s_setprio(0);
    if (t < 15) { VMW8(); } else { VMW4(); }
    BAR();

#pragma unroll
    for (int mi = 0; mi < 4; ++mi)
      af[mi] = *(const bf16x8*)&Asb[(s1 << 13) + ((ar_base + mi * 16) << 5) + q8];
#pragma unroll
    for (int n = 0; n < 4; ++n)
      bfr[n] = *(const bf16x8*)&Bsb[(s1 << 13) + ((br_base + n * 16) << 5) + q8];
    if (t < 15) stageA(sB, t2, 0);
    BAR();
    __builtin_amdgcn_s_setprio(1);
#pragma unroll
    for (int mi = 0; mi < 4; ++mi)
#pragma unroll
      for (int n = 0; n < 4; ++n) acc[mi][n] = mfma16(af[mi], bfr[n], acc[mi][n]);
    __builtin_amdgcn_s_setprio(0);
    BAR();

#pragma unroll
    for (int mi = 0; mi < 4; ++mi)
      af[mi] = *(const bf16x8*)&Asb[(s1 << 13) + ((ar_base + 64 + mi * 16) << 5) + q8];
    if (t < 15) stageB(sB, t2, 0);
    BAR();
    __builtin_amdgcn_s_setprio(1);
#pragma unroll
    for (int mi = 0; mi < 4; ++mi)
#pragma unroll
      for (int n = 0; n < 4; ++n) acc[4 + mi][n] = mfma16(af[mi], bfr[n], acc[4 + mi][n]);
    __builtin_amdgcn_s_setprio(0);
    if (t < 15) VMW8();
    BAR();
  }
  VMW0();

  const int rbase = (int)bm0 + (wm << 7) + ((lane >> 4) << 2);
  const int cbase = (int)bn0 + (wn << 6) + (lane & 15);
#pragma unroll
  for (int n = 0; n < 4; ++n) {
    const int col = cbase + n * 16;
    const float bc = bias[col];
#pragma unroll
    for (int m = 0; m < 8; ++m) {
      const int rb = rbase + m * 16;
#pragma unroll
      for (int i = 0; i < 4; ++i)
        out[(size_t)(rb + i) * 1024 + col] = acc[m][n][i] + bc;
    }
  }
}

// ---------------- kv partial (+ fused sum_k via ones-column) ----------------

__global__ __launch_bounds__(256) void k_kvpart(const unsigned short* __restrict__ kT,
                                                const unsigned short* __restrict__ vT,
                                                float* __restrict__ kvp,
                                                float* __restrict__ sumkp) {
  __shared__ unsigned short Ks[64 * 64];
  __shared__ unsigned short Vs[64 * 64];
  const int blk = blockIdx.x;
  const int bh = blk >> 3, ch = blk & 7;
  const int tid = threadIdx.x, lane = tid & 63, wave = tid >> 6;
  const unsigned short* kb = kT + (size_t)bh * 64 * 4096;
  const unsigned short* vb = vT + (size_t)bh * 64 * 4096;
  const int n0 = ch * 512;
  const int lrow = lane >> 3;
  const int lcolz = (((lane & 7) ^ (lane >> 3)) << 3);
  f32x4 acc[5] = {};

  bf16x8 ones_frag;
  {
    unsigned short o = ((lane & 15) == 0) ? (unsigned short)0x3F80 : (unsigned short)0;
    union { unsigned short u[8]; bf16x8 v; } c;
#pragma unroll
    for (int i = 0; i < 8; ++i) c.u[i] = o;
    ones_frag = c.v;
  }

  const int rxor = (lane & 7) << 3;
  const int col0 = (((lane >> 4) << 3)) ^ rxor;
  const int col1 = ((32 + ((lane >> 4) << 3))) ^ rxor;

  for (int ks = 0; ks < 512; ks += 64) {
    __syncthreads();
#pragma unroll
    for (int i = 0; i < 2; ++i) {
      const int c = i * 4 + wave;
      gload_lds16(kb + (size_t)(c * 8 + lrow) * 4096 + n0 + ks + lcolz, &Ks[c * 512]);
      gload_lds16(vb + (size_t)(c * 8 + lrow) * 4096 + n0 + ks + lcolz, &Vs[c * 512]);
    }
    __syncthreads();
    const int ar = wave * 16 + (lane & 15);
#pragma unroll
    for (int kk = 0; kk < 2; ++kk) {
      const int co = kk ? col1 : col0;
      bf16x8 a = *(const bf16x8*)&Ks[ar * 64 + co];
#pragma unroll
      for (int n = 0; n < 4; ++n) {
        bf16x8 bv = *(const bf16x8*)&Vs[(n * 16 + (lane & 15)) * 64 + co];
        acc[n] = mfma16(a, bv, acc[n]);
      }
      acc[4] = mfma16(a, ones_frag, acc[4]);
    }
  }
  float* dst = kvp + (size_t)blk * 64 * 64;
  const int d0 = wave * 16 + ((lane >> 4) << 2);
#pragma unroll
  for (int n = 0; n < 4; ++n)
#pragma unroll
    for (int i = 0; i < 4; ++i)
      dst[(d0 + i) * 64 + n * 16 + (lane & 15)] = acc[n][i];
  if ((lane & 15) == 0) {
#pragma unroll
    for (int i = 0; i < 4; ++i) sumkp[(size_t)blk * 64 + d0 + i] = acc[4][i];
  }
}

// ---------------- kv reduce ----------------

__global__ __launch_bounds__(256) void k_kvred(const float* __restrict__ kvp,
                                               const float* __restrict__ sumkp,
                                               unsigned short* __restrict__ kvsk) {
  const int bh = blockIdx.x, tid = threadIdx.x;
  const float* src = kvp + (size_t)bh * 8 * 4096;
  unsigned short* dst = kvsk + (size_t)bh * 80 * 64;
#pragma unroll
  for (int it = 0; it < 16; ++it) {
    const int idx = tid + it * 256;
    const int e = idx >> 6, d = idx & 63;
    float s = 0.f;
#pragma unroll
    for (int c = 0; c < 8; ++c) s += src[c * 4096 + d * 64 + e];
    dst[idx] = f2bf(s);
  }
#pragma unroll
  for (int it = 0; it < 4; ++it) {
    const int idx = tid + it * 256;
    const int e2 = idx >> 6, d = idx & 63;
    float v = 0.f;
    if (e2 == 0) {
#pragma unroll
      for (int c = 0; c < 8; ++c) v += sumkp[(size_t)(bh * 8 + c) * 64 + d];
    }
    dst[64 * 64 + idx] = f2bf(v);
  }
}

// ---------------- numerator/denominator/divide ----------------

__global__ __launch_bounds__(256) void k_numer(const unsigned short* __restrict__ qb,
                                               const unsigned short* __restrict__ kvsk,
                                               unsigned short* __restrict__ yb) {
  __shared__ unsigned short Bs[80 * 64];
  const int bh = blockIdx.y;
  const int b = bh >> 4, h = bh & 15;
  const int n0 = blockIdx.x << 7;
  const int tid = threadIdx.x, lane = tid & 63, wave = tid >> 6;
  {
    const uint4* src = (const uint4*)(kvsk + (size_t)bh * 80 * 64);
    uint4* dst = (uint4*)Bs;
    for (int i = tid; i < 640; i += 256) dst[i ^ ((i >> 3) & 7)] = src[i];
  }
  __syncthreads();

  const int ko = (lane >> 4) << 3;
  const int rx = (lane & 7) << 3;
  f32x4 acc[2][5] = {};
  const unsigned short* qrow =
      qb + (size_t)(b * 4096 + n0 + wave * 32 + (lane & 15)) * 1024 + h * 64;
#pragma unroll
  for (int kk = 0; kk < 2; ++kk) {
    bf16x8 a[2], bb[5];
#pragma unroll
    for (int m = 0; m < 2; ++m)
      a[m] = *(const bf16x8*)(qrow + (size_t)m * 16 * 1024 + ko + kk * 32);
#pragma unroll
    for (int n = 0; n < 5; ++n)
      bb[n] = *(const bf16x8*)&Bs[(n * 16 + (lane & 15)) * 64 + ((ko + kk * 32) ^ rx)];
#pragma unroll
    for (int m = 0; m < 2; ++m)
#pragma unroll
      for (int n = 0; n < 5; ++n)
        acc[m][n] = mfma16(a[m], bb[n], acc[m][n]);
  }

  const int rbase = b * 4096 + n0 + wave * 32 + ((lane >> 4) << 2);
#pragma unroll
  for (int m = 0; m < 2; ++m) {
    f32x4 inv;
#pragma unroll
    for (int i = 0; i < 4; ++i) {
      float den = __shfl(acc[m][4][i], lane & 48);
      inv[i] = __builtin_amdgcn_rcpf(den);
    }
#pragma unroll
    for (int n = 0; n < 4; ++n) {
      const int col = h * 64 + n * 16 + (lane & 15);
#pragma unroll
      for (int i = 0; i < 4; ++i)
        yb[(size_t)(rbase + m * 16 + i) * 1024 + col] = f2bf(acc[m][n][i] * inv[i]);
    }
  }
}

// ---------------- launch ----------------

extern "C" void kernel_launch(void* const* d_in, const int* in_sizes, int n_in,
                              void* d_out, int out_size, void* d_ws, size_t ws_size,
                              hipStream_t stream) {
  const float* x = (const float*)d_in[0];
  const float* w_qkv = (const float*)d_in[1];
  const float* w_proj = (const float*)d_in[2];
  const float* b_proj = (const float*)d_in[3];
  float* out = (float*)d_out;
  char* ws = (char*)d_ws;

  unsigned short* yb = (unsigned short*)(ws);                   // 33,554,432 B
  unsigned short* wqkvT = (unsigned short*)(ws + 33554432);     //  6,291,456 B (reused as sumkp)
  unsigned short* wprojT = (unsigned short*)(ws + 39845888);    //  2,097,152 B
  unsigned short* qb = (unsigned short*)(ws + 41943040);        // 33,554,432 B
  unsigned short* kT = (unsigned short*)(ws + 75497472);        // 33,554,432 B
  unsigned short* vT = (unsigned short*)(ws + 109051904);       // 33,554,432 B
  float* kvp = (float*)(ws + 142606336);                        //  8,388,608 B
  unsigned short* kvsk = (unsigned short*)(ws + 151011328);     //    655,360 B
  float* sumkp = (float*)wqkvT;            // wqkvT dead after GEMM1 (512*64*4 B)

  k_cvt_t<<<dim3(96, 32), 256, 0, stream>>>(w_qkv, wqkvT, 1024, 3072);
  k_cvt_t<<<dim3(32, 32), 256, 0, stream>>>(w_proj, wprojT, 1024, 1024);
  k_gemmq<<<768, 512, 65536, stream>>>(x, wqkvT, qb, kT, vT);
  k_kvpart<<<512, 256, 0, stream>>>(kT, vT, kvp, sumkp);
  k_kvred<<<64, 256, 0, stream>>>(kvp, sumkp, kvsk);
  k_numer<<<dim3(32, 64), 256, 0, stream>>>(qb, kvsk, yb);
  k_gemmp<<<256, 512, 131072, stream>>>(yb, wprojT, b_proj, out);
}

// Round 6
// 224.726 us; speedup vs baseline: 6.1781x; 6.1781x over previous
//
#include <hip/hip_runtime.h>

typedef __bf16 bf16x8 __attribute__((ext_vector_type(8)));
typedef float f32x4 __attribute__((ext_vector_type(4)));

typedef const unsigned int __attribute__((address_space(1)))* gas_p;
typedef unsigned int __attribute__((address_space(3)))* las_p;

__device__ __forceinline__ void gload_lds16(const void* g, void* l) {
  __builtin_amdgcn_global_load_lds((gas_p)g, (las_p)l, 16, 0, 0);
}

__device__ __forceinline__ unsigned short f2bf(float f) {
  union { float f; unsigned int u; } x; x.f = f;
  unsigned int r = x.u + 0x7fffu + ((x.u >> 16) & 1u);
  return (unsigned short)(r >> 16);
}
__device__ __forceinline__ float elu1(float x) {
  return x > 0.f ? x + 1.f : __expf(x);
}
__device__ __forceinline__ f32x4 mfma16(bf16x8 a, bf16x8 b, f32x4 c) {
  return __builtin_amdgcn_mfma_f32_16x16x32_bf16(a, b, c, 0, 0, 0);
}

#define BAR() __builtin_amdgcn_s_barrier()
#define VMW8() asm volatile("s_waitcnt vmcnt(8)" ::: "memory")
#define VMW4() asm volatile("s_waitcnt vmcnt(4)" ::: "memory")
#define VMW0() asm volatile("s_waitcnt vmcnt(0)" ::: "memory")
#define LGKM0() do { asm volatile("s_waitcnt lgkmcnt(0)" ::: "memory"); \
                     __builtin_amdgcn_sched_barrier(0); } while (0)

// ---------------- converts ----------------

__global__ __launch_bounds__(256) void k_cvt_x(const float* __restrict__ x,
                                               unsigned short* __restrict__ xb, int n) {
  int i = (blockIdx.x * 256 + threadIdx.x) * 4;
  const int stride = gridDim.x * 256 * 4;
  for (; i < n; i += stride) {
    float4 v = *(const float4*)(x + i);
    union { unsigned short u[4]; uint2 q; } pk;
    pk.u[0] = f2bf(v.x); pk.u[1] = f2bf(v.y); pk.u[2] = f2bf(v.z); pk.u[3] = f2bf(v.w);
    *(uint2*)(xb + i) = pk.q;
  }
}

__global__ __launch_bounds__(256) void k_cvt_t(const float* __restrict__ w,
                                               unsigned short* __restrict__ wT,
                                               int R, int Cc) {
  __shared__ float t[32][33];
  const int j0 = blockIdx.x * 32, i0 = blockIdx.y * 32;
  const int tx = threadIdx.x & 31, ty = threadIdx.x >> 5;
#pragma unroll
  for (int k = 0; k < 4; ++k)
    t[ty + 8 * k][tx] = w[(size_t)(i0 + ty + 8 * k) * Cc + j0 + tx];
  __syncthreads();
#pragma unroll
  for (int k = 0; k < 4; ++k)
    wT[(size_t)(j0 + ty + 8 * k) * R + i0 + tx] = f2bf(t[tx][ty + 8 * k]);
}

// ---------------- 256x256 GEMM, ring-4 pipeline, SINGLE barrier per phase -------------
// LDS: 4 slots/operand of [256 rows][32 K] bf16 (16 KiB). pair g = 2*tile+kk in slot g&3.
// Phase = {ds_read frags; stage-issue; [vmcnt(8)]; lgkmcnt(0); s_barrier; 16 MFMA}.
// Safety: lgkmcnt(0) pre-barrier completes reads before any wave's next stage-issue
// (1 barrier separation); VMW8 at P1/P3 publishes pairs 2 phases before first read.
// Swizzle: col ^= ((row>>1)&3)<<3 elems on read; inverse-swizzled global src (rule 21).

template <int EPI>
__global__ __launch_bounds__(512, 2) void k_gemm256(
    const unsigned short* __restrict__ A, const unsigned short* __restrict__ BT, int NBX,
    unsigned short* __restrict__ qb, unsigned short* __restrict__ kT,
    unsigned short* __restrict__ vT, const float* __restrict__ bias,
    float* __restrict__ out) {
  extern __shared__ unsigned short lds[];
  unsigned short* Asb = lds;           // 4 slots x 8192 elems
  unsigned short* Bsb = lds + 32768;

  const int tid = threadIdx.x, lane = tid & 63, wave = tid >> 6;
  const int wm = wave >> 2, wn = wave & 3;
  int bid = blockIdx.x;
  { const int cpx = (int)gridDim.x >> 3; bid = (bid & 7) * cpx + (bid >> 3); }
  const int bx = bid % NBX, by = bid / NBX;
  const size_t bm0 = (size_t)by << 8, bn0 = (size_t)bx << 8;

  const int srow = (wave << 4) + (lane >> 2);
  const int gscol = ((lane & 3) << 3) ^ (((srow >> 1) & 3) << 3);
  const unsigned short* Ag0 = A + (bm0 + srow) * 1024 + gscol;
  const unsigned short* Bg0 = BT + (bn0 + srow) * 1024 + gscol;
  const int lws = wave << 9;

  auto stageA = [&](int slot, int kt, int kh) {
    const unsigned short* g_ = Ag0 + (kt << 6) + (kh << 5);
    unsigned short* l_ = Asb + (slot << 13) + lws;
    gload_lds16(g_, l_);
    gload_lds16(g_ + 128 * 1024, l_ + 4096);
  };
  auto stageB = [&](int slot, int kt, int kh) {
    const unsigned short* g_ = Bg0 + (kt << 6) + (kh << 5);
    unsigned short* l_ = Bsb + (slot << 13) + lws;
    gload_lds16(g_, l_);
    gload_lds16(g_ + 128 * 1024, l_ + 4096);
  };

  const int q8 = ((lane >> 4) << 3) ^ (((lane >> 1) & 3) << 3);
  const int ar_base = (wm << 7) + (lane & 15);
  const int br_base = (wn << 6) + (lane & 15);

  f32x4 acc[8][4] = {};  // [rh*4+mi][n]

  // prologue: pairs 0,1,2 (A,B interleaved -> in-order drain completes pair 0 first)
  stageA(0, 0, 0); stageB(0, 0, 0);
  stageA(1, 0, 1); stageB(1, 0, 1);
  stageA(2, 1, 0); stageB(2, 1, 0);
  VMW8();  // pair 0 landed
  BAR();

#pragma unroll
  for (int t = 0; t < 16; ++t) {
    const int s0 = (2 * t) & 3, s1 = (2 * t + 1) & 3;
    const int sA = (2 * t + 3) & 3, sB = (2 * t + 4) & 3;
    const int t1 = t + 1, t2 = t + 2;
    bf16x8 af[4], bfr[4];

    // ---- P0: pair s0, rh=0; stage A(t+1,h1) ----
#pragma unroll
    for (int mi = 0; mi < 4; ++mi)
      af[mi] = *(const bf16x8*)&Asb[(s0 << 13) + ((ar_base + mi * 16) << 5) + q8];
#pragma unroll
    for (int n = 0; n < 4; ++n)
      bfr[n] = *(const bf16x8*)&Bsb[(s0 << 13) + ((br_base + n * 16) << 5) + q8];
    if (t < 15) stageA(sA, t1, 1);
    LGKM0();
    BAR();
    __builtin_amdgcn_s_setprio(1);
#pragma unroll
    for (int mi = 0; mi < 4; ++mi)
#pragma unroll
      for (int n = 0; n < 4; ++n) acc[mi][n] = mfma16(af[mi], bfr[n], acc[mi][n]);
    __builtin_amdgcn_s_setprio(0);

    // ---- P1: pair s0, rh=1; stage B(t+1,h1); publish pair 2t+1 ----
#pragma unroll
    for (int mi = 0; mi < 4; ++mi)
      af[mi] = *(const bf16x8*)&Asb[(s0 << 13) + ((ar_base + 64 + mi * 16) << 5) + q8];
    if (t < 15) stageB(sA, t1, 1);
    if (t < 15) { VMW8(); } else { VMW4(); }
    LGKM0();
    BAR();
    __builtin_amdgcn_s_setprio(1);
#pragma unroll
    for (int mi = 0; mi < 4; ++mi)
#pragma unroll
      for (int n = 0; n < 4; ++n) acc[4 + mi][n] = mfma16(af[mi], bfr[n], acc[4 + mi][n]);
    __builtin_amdgcn_s_setprio(0);

    // ---- P2: pair s1, rh=0; stage A(t+2,h0) ----
#pragma unroll
    for (int mi = 0; mi < 4; ++mi)
      af[mi] = *(const bf16x8*)&Asb[(s1 << 13) + ((ar_base + mi * 16) << 5) + q8];
#pragma unroll
    for (int n = 0; n < 4; ++n)
      bfr[n] = *(const bf16x8*)&Bsb[(s1 << 13) + ((br_base + n * 16) << 5) + q8];
    if (t < 14) stageA(sB, t2, 0);
    LGKM0();
    BAR();
    __builtin_amdgcn_s_setprio(1);
#pragma unroll
    for (int mi = 0; mi < 4; ++mi)
#pragma unroll
      for (int n = 0; n < 4; ++n) acc[mi][n] = mfma16(af[mi], bfr[n], acc[mi][n]);
    __builtin_amdgcn_s_setprio(0);

    // ---- P3: pair s1, rh=1; stage B(t+2,h0); publish pair 2t+2 ----
#pragma unroll
    for (int mi = 0; mi < 4; ++mi)
      af[mi] = *(const bf16x8*)&Asb[(s1 << 13) + ((ar_base + 64 + mi * 16) << 5) + q8];
    if (t < 14) stageB(sB, t2, 0);
    if (t < 14) { VMW8(); } else if (t == 14) { VMW4(); }
    LGKM0();
    BAR();
    __builtin_amdgcn_s_setprio(1);
#pragma unroll
    for (int mi = 0; mi < 4; ++mi)
#pragma unroll
      for (int n = 0; n < 4; ++n) acc[4 + mi][n] = mfma16(af[mi], bfr[n], acc[4 + mi][n]);
    __builtin_amdgcn_s_setprio(0);
  }
  VMW0();  // drain any leftover DMA before epilogue/endpgm

  // ---- epilogue ----
  const int rbase = (int)bm0 + (wm << 7) + ((lane >> 4) << 2);
  const int cbase = (int)bn0 + (wn << 6) + (lane & 15);
  if constexpr (EPI == 0) {
    const int reg3 = (int)(bn0 >> 10);  // 0=q 1=k 2=v, uniform per block
#pragma unroll
    for (int m = 0; m < 8; ++m) {
      const int rb = rbase + m * 16;
#pragma unroll
      for (int n = 0; n < 4; ++n) {
        const int col = cbase + n * 16;
        if (reg3 == 0) {
#pragma unroll
          for (int i = 0; i < 4; ++i)
            qb[(size_t)(rb + i) * 1024 + col] = f2bf(elu1(acc[m][n][i]));
        } else {
          const int jc = col & 1023, h = jc >> 6, d = jc & 63;
          const int b_ = rb >> 12, n_ = rb & 4095;
          union { unsigned short u[4]; uint2 q; } pk;
          if (reg3 == 1) {
#pragma unroll
            for (int i = 0; i < 4; ++i) pk.u[i] = f2bf(elu1(acc[m][n][i]));
          } else {
#pragma unroll
            for (int i = 0; i < 4; ++i) pk.u[i] = f2bf(acc[m][n][i]);
          }
          unsigned short* dst = (reg3 == 1) ? kT : vT;
          *(uint2*)(dst + ((size_t)((b_ * 16 + h) * 64 + d) * 4096 + n_)) = pk.q;
        }
      }
    }
  } else {
#pragma unroll
    for (int n = 0; n < 4; ++n) {
      const int col = cbase + n * 16;
      const float bc = bias[col];
#pragma unroll
      for (int m = 0; m < 8; ++m) {
        const int rb = rbase + m * 16;
#pragma unroll
        for (int i = 0; i < 4; ++i)
          out[(size_t)(rb + i) * 1024 + col] = acc[m][n][i] + bc;
      }
    }
  }
}

// ---------------- kv partial (+ fused sum_k via ones-column) ----------------

__global__ __launch_bounds__(256) void k_kvpart(const unsigned short* __restrict__ kT,
                                                const unsigned short* __restrict__ vT,
                                                float* __restrict__ kvp,
                                                float* __restrict__ sumkp) {
  __shared__ unsigned short Ks[64 * 64];
  __shared__ unsigned short Vs[64 * 64];
  const int blk = blockIdx.x;
  const int bh = blk >> 3, ch = blk & 7;
  const int tid = threadIdx.x, lane = tid & 63, wave = tid >> 6;
  const unsigned short* kb = kT + (size_t)bh * 64 * 4096;
  const unsigned short* vb = vT + (size_t)bh * 64 * 4096;
  const int n0 = ch * 512;
  const int lrow = lane >> 3;
  const int lcolz = (((lane & 7) ^ (lane >> 3)) << 3);
  f32x4 acc[5] = {};

  bf16x8 ones_frag;
  {
    unsigned short o = ((lane & 15) == 0) ? (unsigned short)0x3F80 : (unsigned short)0;
    union { unsigned short u[8]; bf16x8 v; } c;
#pragma unroll
    for (int i = 0; i < 8; ++i) c.u[i] = o;
    ones_frag = c.v;
  }

  const int rxor = (lane & 7) << 3;
  const int col0 = (((lane >> 4) << 3)) ^ rxor;
  const int col1 = ((32 + ((lane >> 4) << 3))) ^ rxor;

  for (int ks = 0; ks < 512; ks += 64) {
    __syncthreads();
#pragma unroll
    for (int i = 0; i < 2; ++i) {
      const int c = i * 4 + wave;
      gload_lds16(kb + (size_t)(c * 8 + lrow) * 4096 + n0 + ks + lcolz, &Ks[c * 512]);
      gload_lds16(vb + (size_t)(c * 8 + lrow) * 4096 + n0 + ks + lcolz, &Vs[c * 512]);
    }
    __syncthreads();
    const int ar = wave * 16 + (lane & 15);
#pragma unroll
    for (int kk = 0; kk < 2; ++kk) {
      const int co = kk ? col1 : col0;
      bf16x8 a = *(const bf16x8*)&Ks[ar * 64 + co];
#pragma unroll
      for (int n = 0; n < 4; ++n) {
        bf16x8 bv = *(const bf16x8*)&Vs[(n * 16 + (lane & 15)) * 64 + co];
        acc[n] = mfma16(a, bv, acc[n]);
      }
      acc[4] = mfma16(a, ones_frag, acc[4]);
    }
  }
  float* dst = kvp + (size_t)blk * 64 * 64;
  const int d0 = wave * 16 + ((lane >> 4) << 2);
#pragma unroll
  for (int n = 0; n < 4; ++n)
#pragma unroll
    for (int i = 0; i < 4; ++i)
      dst[(d0 + i) * 64 + n * 16 + (lane & 15)] = acc[n][i];
  if ((lane & 15) == 0) {
#pragma unroll
    for (int i = 0; i < 4; ++i) sumkp[(size_t)blk * 64 + d0 + i] = acc[4][i];
  }
}

// ---------------- kv reduce ----------------

__global__ __launch_bounds__(256) void k_kvred(const float* __restrict__ kvp,
                                               const float* __restrict__ sumkp,
                                               unsigned short* __restrict__ kvsk) {
  const int bh = blockIdx.x, tid = threadIdx.x;
  const float* src = kvp + (size_t)bh * 8 * 4096;
  unsigned short* dst = kvsk + (size_t)bh * 80 * 64;
#pragma unroll
  for (int it = 0; it < 16; ++it) {
    const int idx = tid + it * 256;
    const int e = idx >> 6, d = idx & 63;
    float s = 0.f;
#pragma unroll
    for (int c = 0; c < 8; ++c) s += src[c * 4096 + d * 64 + e];
    dst[idx] = f2bf(s);
  }
#pragma unroll
  for (int it = 0; it < 4; ++it) {
    const int idx = tid + it * 256;
    const int e2 = idx >> 6, d = idx & 63;
    float v = 0.f;
    if (e2 == 0) {
#pragma unroll
      for (int c = 0; c < 8; ++c) v += sumkp[(size_t)(bh * 8 + c) * 64 + d];
    }
    dst[64 * 64 + idx] = f2bf(v);
  }
}

// ---------------- numerator/denominator/divide ----------------

__global__ __launch_bounds__(256) void k_numer(const unsigned short* __restrict__ qb,
                                               const unsigned short* __restrict__ kvsk,
                                               unsigned short* __restrict__ yb) {
  __shared__ unsigned short Bs[80 * 64];
  const int bh = blockIdx.y;
  const int b = bh >> 4, h = bh & 15;
  const int n0 = blockIdx.x << 7;
  const int tid = threadIdx.x, lane = tid & 63, wave = tid >> 6;
  {
    const uint4* src = (const uint4*)(kvsk + (size_t)bh * 80 * 64);
    uint4* dst = (uint4*)Bs;
    for (int i = tid; i < 640; i += 256) dst[i ^ ((i >> 3) & 7)] = src[i];
  }
  __syncthreads();

  const int ko = (lane >> 4) << 3;
  const int rx = (lane & 7) << 3;
  f32x4 acc[2][5] = {};
  const unsigned short* qrow =
      qb + (size_t)(b * 4096 + n0 + wave * 32 + (lane & 15)) * 1024 + h * 64;
#pragma unroll
  for (int kk = 0; kk < 2; ++kk) {
    bf16x8 a[2], bb[5];
#pragma unroll
    for (int m = 0; m < 2; ++m)
      a[m] = *(const bf16x8*)(qrow + (size_t)m * 16 * 1024 + ko + kk * 32);
#pragma unroll
    for (int n = 0; n < 5; ++n)
      bb[n] = *(const bf16x8*)&Bs[(n * 16 + (lane & 15)) * 64 + ((ko + kk * 32) ^ rx)];
#pragma unroll
    for (int m = 0; m < 2; ++m)
#pragma unroll
      for (int n = 0; n < 5; ++n)
        acc[m][n] = mfma16(a[m], bb[n], acc[m][n]);
  }

  const int rbase = b * 4096 + n0 + wave * 32 + ((lane >> 4) << 2);
#pragma unroll
  for (int m = 0; m < 2; ++m) {
    f32x4 inv;
#pragma unroll
    for (int i = 0; i < 4; ++i) {
      float den = __shfl(acc[m][4][i], lane & 48);
      inv[i] = __builtin_amdgcn_rcpf(den);
    }
#pragma unroll
    for (int n = 0; n < 4; ++n) {
      const int col = h * 64 + n * 16 + (lane & 15);
#pragma unroll
      for (int i = 0; i < 4; ++i)
        yb[(size_t)(rbase + m * 16 + i) * 1024 + col] = f2bf(acc[m][n][i] * inv[i]);
    }
  }
}

// ---------------- launch ----------------

extern "C" void kernel_launch(void* const* d_in, const int* in_sizes, int n_in,
                              void* d_out, int out_size, void* d_ws, size_t ws_size,
                              hipStream_t stream) {
  const float* x = (const float*)d_in[0];
  const float* w_qkv = (const float*)d_in[1];
  const float* w_proj = (const float*)d_in[2];
  const float* b_proj = (const float*)d_in[3];
  float* out = (float*)d_out;
  char* ws = (char*)d_ws;

  unsigned short* xb = (unsigned short*)(ws);                   // 33,554,432 B (reused as yb)
  unsigned short* wqkvT = (unsigned short*)(ws + 33554432);     //  6,291,456 B (reused as sumkp)
  unsigned short* wprojT = (unsigned short*)(ws + 39845888);    //  2,097,152 B
  unsigned short* qb = (unsigned short*)(ws + 41943040);        // 33,554,432 B
  unsigned short* kT = (unsigned short*)(ws + 75497472);        // 33,554,432 B
  unsigned short* vT = (unsigned short*)(ws + 109051904);       // 33,554,432 B
  float* kvp = (float*)(ws + 142606336);                        //  8,388,608 B
  unsigned short* kvsk = (unsigned short*)(ws + 151011328);     //    655,360 B
  unsigned short* yb = xb;                 // xb dead after GEMM1
  float* sumkp = (float*)wqkvT;            // wqkvT dead after GEMM1 (512*64*4 B)

  k_cvt_x<<<2048, 256, 0, stream>>>(x, xb, 4 * 4096 * 1024);
  k_cvt_t<<<dim3(96, 32), 256, 0, stream>>>(w_qkv, wqkvT, 1024, 3072);
  k_cvt_t<<<dim3(32, 32), 256, 0, stream>>>(w_proj, wprojT, 1024, 1024);
  k_gemm256<0><<<768, 512, 131072, stream>>>(xb, wqkvT, 12, qb, kT, vT, nullptr, nullptr);
  k_kvpart<<<512, 256, 0, stream>>>(kT, vT, kvp, sumkp);
  k_kvred<<<64, 256, 0, stream>>>(kvp, sumkp, kvsk);
  k_numer<<<dim3(32, 64), 256, 0, stream>>>(qb, kvsk, yb);
  k_gemm256<1><<<256, 512, 131072, stream>>>(yb, wprojT, 4, nullptr, nullptr, nullptr,
                                             b_proj, out);
}